// Round 8
// baseline (6711.245 us; speedup 1.0000x reference)
//
#include <hip/hip_runtime.h>
#include <math.h>

#define BB 32
#define TT 50
#define CC 501
#define NNODES (BB*CC)          // 16032
#define BN_SCALEF 0.9999950000374996f
#define NSTEP (TT-1)            // 49

// persistent kernel geometry: 501 blocks x 256 threads (4 waves); each wave
// does 8 nodes (V=4 per 32-lane half). 32 nodes/block, 501*32 = 16032 exact.
// __launch_bounds__(256,2): hard VGPR cap 256 => 2 waves/SIMD => 2 blocks/CU
// guaranteed resident (LDS 2x60KB=120KB<=160KB) => 512 slots >= 501 blocks,
// so the grid barrier cannot deadlock.
#define V 4
#define WPB 4
#define NTH 256
#define NPB 32
#define NBLK 501

// workspace layout (floats)
#define HT_SZ   (NNODES*32)     // 513024
#define P_SZ    (CC*32)         // 16032
#define GT_SZ   (CC*CC)         // 251001
#define PERB_BUF (BB*96)        // per buffer, double buffered (2 bufs)

struct Params {
    const int* features; const int* questions;
    const float* graph;  const float* emb_x;
    const float* self_w1; const float* self_b1; const float* self_w2; const float* self_b2;
    const float* n0_w1; const float* n0_b1; const float* n0_w2; const float* n0_b2;
    const float* n1_w1; const float* n1_b1; const float* n1_w2; const float* n1_b2;
    const float* ea_w; const float* ea_ew; const float* ea_eb; const float* ea_aw; const float* ea_ab;
    const float* gru_w_ih; const float* gru_w_hh; const float* gru_b_ih; const float* gru_b_hh;
    const float* pred_w; const float* pred_b;
    float* ht; const float* P0; const float* P1; const float* graphT;
    float* perb; float* out; unsigned* bar;
};

__device__ __forceinline__ float dot4(float4 a, float4 b){
    return a.x*b.x + a.y*b.y + a.z*b.z + a.w*b.w;
}
__device__ __forceinline__ float sigm(float x){ return 1.f/(1.f+__expf(-x)); }
__device__ __forceinline__ float tanhfast(float x){ return 1.f - 2.f/(__expf(2.f*x)+1.f); }

// ---------------- init: zero ht + transpose graph + zero barriers ----------------
__global__ void init0_kernel(const float* __restrict__ graph,
                             float* __restrict__ graphT,
                             float* __restrict__ ht,
                             unsigned* __restrict__ bar) {
    int i = blockIdx.x*blockDim.x + threadIdx.x;
    if (i < HT_SZ) ht[i] = 0.f;
    if (i < GT_SZ) {
        int r = i / CC, c2 = i % CC;       // graphT[r][c2] = graph[c2][r]
        graphT[i] = graph[c2*CC + r];
    }
    if (i < 64) bar[i] = 0u;
}

// ---------------- init: P0/P1 (per-concept const part of layer1) ----------------
__global__ void pk_kernel(const float* __restrict__ n0_w1, const float* __restrict__ n1_w1,
                          const float* __restrict__ emb_c,
                          float* __restrict__ P0, float* __restrict__ P1) {
    int c = blockIdx.x;
    int which = threadIdx.x >> 5, j = threadIdx.x & 31;
    float ec = emb_c[c*32 + j];
    const float* W = which ? n1_w1 : n0_w1;
    float acc = 0.f;
    #pragma unroll
    for (int k = 0; k < 32; k++)
        acc += W[j*128 + 96 + k] * __shfl(ec, k, 32);
    (which ? P1 : P0)[c*32 + j] = acc;
}

// ---------------- init: per-b quantities for step 0 (h_q = 0) ----------------
__global__ void perb0_kernel(const int* __restrict__ features, const float* __restrict__ emb_x,
                             const float* __restrict__ n0_w1, const float* __restrict__ n0_b1,
                             const float* __restrict__ n1_w1, const float* __restrict__ n1_b1,
                             const float* __restrict__ self_w1, const float* __restrict__ self_b1,
                             const float* __restrict__ self_w2, const float* __restrict__ self_b2,
                             float* __restrict__ perb) {
    int b = threadIdx.x >> 5, j = threadIdx.x & 31;
    int xt = features[b*TT + 0];
    float eq = emb_x[xt*32 + j];
    float a0 = n0_b1[j], a1 = n1_b1[j], s = self_b1[j];
    #pragma unroll
    for (int k = 0; k < 32; k++) {
        float ek = __shfl(eq, k, 32);
        a0 += n0_w1[j*128 + 32 + k] * ek;
        a1 += n1_w1[j*128 + 32 + k] * ek;
        s  += self_w1[j*64 + 32 + k] * ek;
    }
    float l1 = fmaxf(s, 0.f);
    float s2 = self_b2[j];
    #pragma unroll
    for (int k = 0; k < 32; k++) s2 += self_w2[j*32 + k] * __shfl(l1, k, 32);
    perb[b*96 + j]      = a0;
    perb[b*96 + 32 + j] = a1;
    perb[b*96 + 64 + j] = fmaxf(s2, 0.f) * BN_SCALEF;
}

// ---------------- grid barrier (per-step fresh counter, agent-scope fences) ----------------
__device__ __forceinline__ void gbar(unsigned* ctr) {
    __builtin_amdgcn_fence(__ATOMIC_RELEASE, "agent");
    __syncthreads();
    if (threadIdx.x == 0) {
        __hip_atomic_fetch_add(ctr, 1u, __ATOMIC_RELAXED, __HIP_MEMORY_SCOPE_AGENT);
        while (__hip_atomic_load(ctr, __ATOMIC_RELAXED, __HIP_MEMORY_SCOPE_AGENT) < (unsigned)NBLK) {
            __builtin_amdgcn_s_sleep(2);
        }
    }
    __syncthreads();
    __builtin_amdgcn_fence(__ATOMIC_ACQUIRE, "agent");
}

// ---------------- persistent all-steps kernel ----------------
__global__ __launch_bounds__(NTH, 2) void fused_kernel(Params p) {
    // Weight LDS, chunked-transposed: lane j reads float4 at [kc*128 + j*4]
    //  [0,1024)    Ch0 (n0_w1 cols 64:96)   [1024,2048) Ch1
    //  [2048,3072) W20 (n0_w2)              [3072,4096) W21
    //  [4096,5120) EW (ea_ew)               [5120,6144) AW (ea_aw)
    //  [6144,9216) Wih (96 rows) [kc][row][4]   [9216,12288) Whh
    __shared__ float Wq[12288];
    __shared__ float xb[WPB][3][8][32];    // per-wave x buffers (h, t0/m, t1/m')

    int tid = threadIdx.x;
    for (int idx = tid; idx < 12288; idx += NTH) {
        float v;
        if (idx < 6144) {
            int region = idx >> 10;
            int r = idx & 1023;
            int jj = (r >> 2) & 31;
            int k = ((r >> 7) << 2) | (r & 3);
            switch (region) {
                case 0:  v = p.n0_w1[jj*128 + 64 + k]; break;
                case 1:  v = p.n1_w1[jj*128 + 64 + k]; break;
                case 2:  v = p.n0_w2[jj*32 + k]; break;
                case 3:  v = p.n1_w2[jj*32 + k]; break;
                case 4:  v = p.ea_ew[jj*32 + k]; break;
                default: v = p.ea_aw[jj*32 + k]; break;
            }
            Wq[idx] = v;
        } else {
            int r = idx - 6144;
            int which = r / 3072;
            int r2 = r % 3072;
            int row = (r2 >> 2) % 96;
            int k = ((r2 / 384) << 2) | (r2 & 3);
            Wq[idx] = which ? p.gru_w_hh[row*32 + k] : p.gru_w_ih[row*32 + k];
        }
    }
    __syncthreads();

    int l = tid & 63;
    int w = tid >> 6;
    int j = l & 31, sub = l >> 5;
    int nodebase = blockIdx.x*NPB + w*8;   // exact cover: 501*32 = 16032

    for (int t = 0; t < NSTEP; t++) {
        int pbase = (t & 1)*PERB_BUF;

        // ---- prologue: load h, adj, radj ----
        float hj[V], adjv[V], radjv[V];
        #pragma unroll
        for (int v = 0; v < V; v++) {
            int node = nodebase + 2*v + sub;
            int b = node / CC, c = node - b*CC;
            int qt = p.questions[b*TT + t];
            adjv[v]  = p.graph [qt*CC + c];
            radjv[v] = p.graphT[qt*CC + c];
            float h = p.ht[node*32 + j];
            hj[v] = h;
            xb[w][0][2*v+sub][j] = h;
        }

        // ---- fused phase 1 + 4a: acc0/acc1 (neigh L1) and gh0..2 (GRU hh) from h ----
        float gh0[V], gh1[V], gh2[V];
        {
            float acc0[V], acc1[V];
            float bh0 = p.gru_b_hh[j], bh1 = p.gru_b_hh[32+j], bh2 = p.gru_b_hh[64+j];
            #pragma unroll
            for (int v = 0; v < V; v++) {
                int node = nodebase + 2*v + sub;
                int b = node / CC, c = node - b*CC;
                acc0[v] = p.perb[pbase + b*96 + j]      + p.P0[c*32 + j];
                acc1[v] = p.perb[pbase + b*96 + 32 + j] + p.P1[c*32 + j];
                gh0[v] = bh0; gh1[v] = bh1; gh2[v] = bh2;
            }
            #pragma unroll
            for (int kc = 0; kc < 8; kc++) {
                float4 w0  = *(const float4*)&Wq[       kc*128 + j*4];
                float4 w1  = *(const float4*)&Wq[1024 + kc*128 + j*4];
                const float* wh = &Wq[9216 + kc*384];
                float4 wh0 = *(const float4*)&wh[j*4];
                float4 wh1 = *(const float4*)&wh[(32+j)*4];
                float4 wh2 = *(const float4*)&wh[(64+j)*4];
                #pragma unroll
                for (int v = 0; v < V; v++) {
                    float4 x = *(const float4*)&xb[w][0][2*v+sub][kc*4];
                    acc0[v] += dot4(w0, x);
                    acc1[v] += dot4(w1, x);
                    gh0[v] += dot4(wh0, x);
                    gh1[v] += dot4(wh1, x);
                    gh2[v] += dot4(wh2, x);
                }
            }
            #pragma unroll
            for (int v = 0; v < V; v++) {
                xb[w][1][2*v+sub][j] = fmaxf(acc0[v], 0.f);
                xb[w][2][2*v+sub][j] = fmaxf(acc1[v], 0.f);
            }
        }

        // ---- phase 2: f=relu(W2@t)*BN; m = adj*f0+radj*f1 (self ovr) ----
        {
            float a0[V], a1[V];
            float b0 = p.n0_b2[j], b1 = p.n1_b2[j];
            #pragma unroll
            for (int v = 0; v < V; v++) { a0[v] = b0; a1[v] = b1; }
            #pragma unroll
            for (int kc = 0; kc < 8; kc++) {
                float4 w0 = *(const float4*)&Wq[2048 + kc*128 + j*4];
                float4 w1 = *(const float4*)&Wq[3072 + kc*128 + j*4];
                #pragma unroll
                for (int v = 0; v < V; v++) {
                    float4 va = *(const float4*)&xb[w][1][2*v+sub][kc*4];
                    float4 vb = *(const float4*)&xb[w][2][2*v+sub][kc*4];
                    a0[v] += dot4(w0, va);
                    a1[v] += dot4(w1, vb);
                }
            }
            #pragma unroll
            for (int v = 0; v < V; v++) {
                int node = nodebase + 2*v + sub;
                int b = node / CC, c = node - b*CC;
                int qt = p.questions[b*TT + t];
                float f0 = fmaxf(a0[v], 0.f) * BN_SCALEF;
                float f1 = fmaxf(a1[v], 0.f) * BN_SCALEF;
                float m = adjv[v]*f0 + radjv[v]*f1;
                if (c == qt) m = p.perb[pbase + b*96 + 64 + j];
                xb[w][1][2*v+sub][j] = m;
            }
        }

        // ---- phase 3: edge attention -> m' in xb[2] ----
        {
            float e[V], aa[V];
            float be = p.ea_eb[j], ba = p.ea_ab[j];
            #pragma unroll
            for (int v = 0; v < V; v++) { e[v] = be; aa[v] = ba; }
            #pragma unroll
            for (int kc = 0; kc < 8; kc++) {
                float4 we = *(const float4*)&Wq[4096 + kc*128 + j*4];
                float4 wa = *(const float4*)&Wq[5120 + kc*128 + j*4];
                #pragma unroll
                for (int v = 0; v < V; v++) {
                    float4 vm = *(const float4*)&xb[w][1][2*v+sub][kc*4];
                    e[v]  += dot4(we, vm);
                    aa[v] += dot4(wa, vm);
                }
            }
            #pragma unroll
            for (int v = 0; v < V; v++) {
                int node = nodebase + 2*v + sub;
                int b = node / CC, c = node - b*CC;
                float eg = sigm(e[v]);
                float af = tanhfast(aa[v]);
                float wc = p.ea_w[c];
                float m  = xb[w][1][2*v+sub][j];
                xb[w][2][2*v+sub][j] = m - wc*eg*m + wc*af;
            }
        }

        // ---- phase 4b: GRU ih gates from m'; combine with gh regs; write ht ----
        float hn[V];
        {
            float gi0[V], gi1[V], gi2[V];
            float bi0 = p.gru_b_ih[j], bi1 = p.gru_b_ih[32+j], bi2 = p.gru_b_ih[64+j];
            #pragma unroll
            for (int v = 0; v < V; v++) { gi0[v]=bi0; gi1[v]=bi1; gi2[v]=bi2; }
            #pragma unroll
            for (int kc = 0; kc < 8; kc++) {
                const float* wi = &Wq[6144 + kc*384];
                float4 wi0 = *(const float4*)&wi[j*4];
                float4 wi1 = *(const float4*)&wi[(32+j)*4];
                float4 wi2 = *(const float4*)&wi[(64+j)*4];
                #pragma unroll
                for (int v = 0; v < V; v++) {
                    float4 vm = *(const float4*)&xb[w][2][2*v+sub][kc*4];
                    gi0[v] += dot4(wi0, vm);
                    gi1[v] += dot4(wi1, vm);
                    gi2[v] += dot4(wi2, vm);
                }
            }
            #pragma unroll
            for (int v = 0; v < V; v++) {
                float r = sigm(gi0[v] + gh0[v]);
                float z = sigm(gi1[v] + gh1[v]);
                float n = tanhfast(gi2[v] + r*gh2[v]);
                hn[v] = (1.f - z)*n + z*hj[v];
                int node = nodebase + 2*v + sub;
                p.ht[node*32 + j] = hn[v];
            }
        }

        // ---- phase 5: prediction + per-b prep for step t+1 ----
        #pragma unroll
        for (int v = 0; v < V; v++) {
            int node = nodebase + 2*v + sub;
            int b = node / CC, c = node - b*CC;
            int qn = p.questions[b*TT + t + 1];
            if (c == qn) {                  // uniform within 32-lane half
                float s = hn[v] * p.pred_w[j];
                #pragma unroll
                for (int off = 16; off; off >>= 1) s += __shfl_down(s, off, 32);
                if (j == 0) p.out[b*(TT-1) + t] = sigm(s + p.pred_b[0]);

                if (t < TT - 2) {
                    int xt1 = p.features[b*TT + t + 1];
                    float eq = p.emb_x[xt1*32 + j];
                    float accA0 = p.n0_b1[j], accA1 = p.n1_b1[j], accS = p.self_b1[j];
                    #pragma unroll
                    for (int k = 0; k < 32; k++) {
                        float hk = __shfl(hn[v], k, 32);
                        float ek = __shfl(eq, k, 32);
                        accA0 += p.n0_w1[j*128 + k]*hk + p.n0_w1[j*128 + 32 + k]*ek;
                        accA1 += p.n1_w1[j*128 + k]*hk + p.n1_w1[j*128 + 32 + k]*ek;
                        accS  += p.self_w1[j*64 + k]*hk + p.self_w1[j*64 + 32 + k]*ek;
                    }
                    float l1 = fmaxf(accS, 0.f);
                    float s2 = p.self_b2[j];
                    #pragma unroll
                    for (int k = 0; k < 32; k++) s2 += p.self_w2[j*32 + k] * __shfl(l1, k, 32);
                    float* pn = p.perb + ((t+1) & 1)*PERB_BUF + b*96;
                    pn[j]      = accA0;
                    pn[32 + j] = accA1;
                    pn[64 + j] = fmaxf(s2, 0.f) * BN_SCALEF;
                }
            }
        }

        if (t != NSTEP - 1) gbar(p.bar + t);
    }
}

extern "C" void kernel_launch(void* const* d_in, const int* in_sizes, int n_in,
                              void* d_out, int out_size, void* d_ws, size_t ws_size,
                              hipStream_t stream) {
    Params prm;
    prm.features = (const int*)  d_in[0];
    prm.questions= (const int*)  d_in[1];
    prm.graph    = (const float*)d_in[2];
    prm.emb_x    = (const float*)d_in[3];
    const float* emb_c = (const float*)d_in[4];
    prm.self_w1  = (const float*)d_in[5];
    prm.self_b1  = (const float*)d_in[6];
    prm.self_w2  = (const float*)d_in[7];
    prm.self_b2  = (const float*)d_in[8];
    prm.n0_w1    = (const float*)d_in[9];
    prm.n0_b1    = (const float*)d_in[10];
    prm.n0_w2    = (const float*)d_in[11];
    prm.n0_b2    = (const float*)d_in[12];
    prm.n1_w1    = (const float*)d_in[13];
    prm.n1_b1    = (const float*)d_in[14];
    prm.n1_w2    = (const float*)d_in[15];
    prm.n1_b2    = (const float*)d_in[16];
    prm.ea_w     = (const float*)d_in[17];
    prm.ea_ew    = (const float*)d_in[18];
    prm.ea_eb    = (const float*)d_in[19];
    prm.ea_aw    = (const float*)d_in[20];
    prm.ea_ab    = (const float*)d_in[21];
    prm.gru_w_ih = (const float*)d_in[22];
    prm.gru_w_hh = (const float*)d_in[23];
    prm.gru_b_ih = (const float*)d_in[24];
    prm.gru_b_hh = (const float*)d_in[25];
    prm.pred_w   = (const float*)d_in[26];
    prm.pred_b   = (const float*)d_in[27];
    prm.out = (float*)d_out;

    float* ws   = (float*)d_ws;
    prm.ht      = ws;
    float* P0   = prm.ht + HT_SZ;
    float* P1   = P0 + P_SZ;
    float* gT   = P1 + P_SZ;
    float* perb = gT + GT_SZ;
    unsigned* bar = (unsigned*)(perb + 2*PERB_BUF);
    prm.P0 = P0; prm.P1 = P1; prm.graphT = gT; prm.perb = perb; prm.bar = bar;

    init0_kernel<<<(HT_SZ + 255)/256, 256, 0, stream>>>(prm.graph, gT, prm.ht, bar);
    pk_kernel<<<CC, 64, 0, stream>>>(prm.n0_w1, prm.n1_w1, emb_c, P0, P1);
    perb0_kernel<<<1, 1024, 0, stream>>>(prm.features, prm.emb_x,
        prm.n0_w1, prm.n0_b1, prm.n1_w1, prm.n1_b1,
        prm.self_w1, prm.self_b1, prm.self_w2, prm.self_b2, perb);

    fused_kernel<<<NBLK, NTH, 0, stream>>>(prm);
}

// Round 9
// 1269.845 us; speedup vs baseline: 5.2851x; 5.2851x over previous
//
#include <hip/hip_runtime.h>
#include <math.h>

#define BB 32
#define TT 50
#define CC 501
#define NNODES (BB*CC)          // 16032
#define BN_SCALEF 0.9999950000374996f
#define NSTEP (TT-1)            // 49

// step kernel geometry: 501 blocks x 256 threads (4 waves); each wave does
// 8 nodes (V=4 per 32-lane half). 501*32 = 16032 exact. Per-step launches:
// no residency assumptions, no grid barrier. (256,1) => VGPR free to 512,
// avoids the 128-cap/spill pathology of any >=2-waves/EU launch_bounds.
#define V 4
#define WPB 4
#define NTH 256
#define NPB 32
#define NBLK 501
#define WQN 12288               // packed weight floats (48 KB)

// workspace layout (floats)
#define HT_SZ   (NNODES*32)     // 513024
#define P_SZ    (CC*32)         // 16032
#define GT_SZ   (CC*CC)         // 251001
#define PERB_BUF (BB*96)        // per buffer, double buffered (2 bufs)

struct Params {
    const int* features; const int* questions;
    const float* graph;  const float* emb_x;
    const float* self_w1; const float* self_b1; const float* self_w2; const float* self_b2;
    const float* n0_w1; const float* n0_b1; const float* n0_w2; const float* n0_b2;
    const float* n1_w1; const float* n1_b1; const float* n1_w2; const float* n1_b2;
    const float* ea_w; const float* ea_ew; const float* ea_eb; const float* ea_aw; const float* ea_ab;
    const float* gru_w_ih; const float* gru_w_hh; const float* gru_b_ih; const float* gru_b_hh;
    const float* pred_w; const float* pred_b;
    float* ht; const float* P0; const float* P1; const float* graphT;
    float* perb; float* out; const float* wpack;
};

__device__ __forceinline__ float dot4(float4 a, float4 b){
    return a.x*b.x + a.y*b.y + a.z*b.z + a.w*b.w;
}
__device__ __forceinline__ float sigm(float x){ return 1.f/(1.f+__expf(-x)); }
__device__ __forceinline__ float tanhfast(float x){ return 1.f - 2.f/(__expf(2.f*x)+1.f); }

// ---------------- init: zero ht + transpose graph ----------------
__global__ void init0_kernel(const float* __restrict__ graph,
                             float* __restrict__ graphT,
                             float* __restrict__ ht) {
    int i = blockIdx.x*blockDim.x + threadIdx.x;
    if (i < HT_SZ) ht[i] = 0.f;
    if (i < GT_SZ) {
        int r = i / CC, c2 = i % CC;       // graphT[r][c2] = graph[c2][r]
        graphT[i] = graph[c2*CC + r];
    }
}

// ---------------- init: P0/P1 (per-concept const part of layer1) ----------------
__global__ void pk_kernel(const float* __restrict__ n0_w1, const float* __restrict__ n1_w1,
                          const float* __restrict__ emb_c,
                          float* __restrict__ P0, float* __restrict__ P1) {
    int c = blockIdx.x;
    int which = threadIdx.x >> 5, j = threadIdx.x & 31;
    float ec = emb_c[c*32 + j];
    const float* W = which ? n1_w1 : n0_w1;
    float acc = 0.f;
    #pragma unroll
    for (int k = 0; k < 32; k++)
        acc += W[j*128 + 96 + k] * __shfl(ec, k, 32);
    (which ? P1 : P0)[c*32 + j] = acc;
}

// ---------------- init: pack weights into the Wq linear layout ----------------
//  [0,1024)    Ch0 (n0_w1 cols 64:96) [kc][j][4]   [1024,2048) Ch1
//  [2048,3072) W20 (n0_w2)                         [3072,4096) W21
//  [4096,5120) EW (ea_ew)                          [5120,6144) AW (ea_aw)
//  [6144,9216) Wih (96 rows) [kc][row][4]          [9216,12288) Whh
__global__ void pack_kernel(const float* __restrict__ n0_w1, const float* __restrict__ n1_w1,
                            const float* __restrict__ n0_w2, const float* __restrict__ n1_w2,
                            const float* __restrict__ ea_ew, const float* __restrict__ ea_aw,
                            const float* __restrict__ gru_w_ih, const float* __restrict__ gru_w_hh,
                            float* __restrict__ wpack) {
    for (int idx = threadIdx.x; idx < WQN; idx += 256) {
        float v;
        if (idx < 6144) {
            int region = idx >> 10;
            int r = idx & 1023;
            int jj = (r >> 2) & 31;
            int k = ((r >> 7) << 2) | (r & 3);
            switch (region) {
                case 0:  v = n0_w1[jj*128 + 64 + k]; break;
                case 1:  v = n1_w1[jj*128 + 64 + k]; break;
                case 2:  v = n0_w2[jj*32 + k]; break;
                case 3:  v = n1_w2[jj*32 + k]; break;
                case 4:  v = ea_ew[jj*32 + k]; break;
                default: v = ea_aw[jj*32 + k]; break;
            }
        } else {
            int r = idx - 6144;
            int which = r / 3072;
            int r2 = r % 3072;
            int row = (r2 >> 2) % 96;
            int k = ((r2 / 384) << 2) | (r2 & 3);
            v = which ? gru_w_hh[row*32 + k] : gru_w_ih[row*32 + k];
        }
        wpack[idx] = v;
    }
}

// ---------------- init: per-b quantities for step 0 (h_q = 0) ----------------
__global__ void perb0_kernel(const int* __restrict__ features, const float* __restrict__ emb_x,
                             const float* __restrict__ n0_w1, const float* __restrict__ n0_b1,
                             const float* __restrict__ n1_w1, const float* __restrict__ n1_b1,
                             const float* __restrict__ self_w1, const float* __restrict__ self_b1,
                             const float* __restrict__ self_w2, const float* __restrict__ self_b2,
                             float* __restrict__ perb) {
    int b = threadIdx.x >> 5, j = threadIdx.x & 31;
    int xt = features[b*TT + 0];
    float eq = emb_x[xt*32 + j];
    float a0 = n0_b1[j], a1 = n1_b1[j], s = self_b1[j];
    #pragma unroll
    for (int k = 0; k < 32; k++) {
        float ek = __shfl(eq, k, 32);
        a0 += n0_w1[j*128 + 32 + k] * ek;
        a1 += n1_w1[j*128 + 32 + k] * ek;
        s  += self_w1[j*64 + 32 + k] * ek;
    }
    float l1 = fmaxf(s, 0.f);
    float s2 = self_b2[j];
    #pragma unroll
    for (int k = 0; k < 32; k++) s2 += self_w2[j*32 + k] * __shfl(l1, k, 32);
    perb[b*96 + j]      = a0;
    perb[b*96 + 32 + j] = a1;
    perb[b*96 + 64 + j] = fmaxf(s2, 0.f) * BN_SCALEF;
}

// ---------------- one recurrence step ----------------
__global__ __launch_bounds__(NTH, 1) void step_kernel(int t, Params p) {
    __shared__ float Wq[WQN];
    __shared__ float xb[WPB][3][8][32];    // per-wave x buffers (h, t0/m, t1/m')

    int tid = threadIdx.x;
    {   // fast staging: packed weights -> LDS, 12 x float4 per thread
        const float4* wp4 = (const float4*)p.wpack;
        float4* Wq4 = (float4*)Wq;
        #pragma unroll
        for (int i = 0; i < 12; i++) Wq4[tid + i*NTH] = wp4[tid + i*NTH];
    }
    __syncthreads();

    int l = tid & 63;
    int w = tid >> 6;
    int j = l & 31, sub = l >> 5;
    int nodebase = blockIdx.x*NPB + w*8;   // exact cover: 501*32 = 16032
    int pbase = (t & 1)*PERB_BUF;

    // ---- prologue: node metadata + h, adj, radj ----
    int bv[V], cv[V], qtv[V];
    float hj[V], adjv[V], radjv[V];
    #pragma unroll
    for (int v = 0; v < V; v++) {
        int node = nodebase + 2*v + sub;
        int b = node / CC, c = node - b*CC;
        bv[v] = b; cv[v] = c;
        int qt = p.questions[b*TT + t];
        qtv[v] = qt;
        adjv[v]  = p.graph [qt*CC + c];
        radjv[v] = p.graphT[qt*CC + c];
        float h = p.ht[node*32 + j];
        hj[v] = h;
        xb[w][0][2*v+sub][j] = h;
    }

    // ---- fused phase 1 + 4a: acc0/acc1 (neigh L1) and gh0..2 (GRU hh) from h ----
    float gh0[V], gh1[V], gh2[V];
    {
        float acc0[V], acc1[V];
        float bh0 = p.gru_b_hh[j], bh1 = p.gru_b_hh[32+j], bh2 = p.gru_b_hh[64+j];
        #pragma unroll
        for (int v = 0; v < V; v++) {
            acc0[v] = p.perb[pbase + bv[v]*96 + j]      + p.P0[cv[v]*32 + j];
            acc1[v] = p.perb[pbase + bv[v]*96 + 32 + j] + p.P1[cv[v]*32 + j];
            gh0[v] = bh0; gh1[v] = bh1; gh2[v] = bh2;
        }
        #pragma unroll
        for (int kc = 0; kc < 8; kc++) {
            float4 w0  = *(const float4*)&Wq[       kc*128 + j*4];
            float4 w1  = *(const float4*)&Wq[1024 + kc*128 + j*4];
            const float* wh = &Wq[9216 + kc*384];
            float4 wh0 = *(const float4*)&wh[j*4];
            float4 wh1 = *(const float4*)&wh[(32+j)*4];
            float4 wh2 = *(const float4*)&wh[(64+j)*4];
            #pragma unroll
            for (int v = 0; v < V; v++) {
                float4 x = *(const float4*)&xb[w][0][2*v+sub][kc*4];
                acc0[v] += dot4(w0, x);
                acc1[v] += dot4(w1, x);
                gh0[v] += dot4(wh0, x);
                gh1[v] += dot4(wh1, x);
                gh2[v] += dot4(wh2, x);
            }
        }
        #pragma unroll
        for (int v = 0; v < V; v++) {
            xb[w][1][2*v+sub][j] = fmaxf(acc0[v], 0.f);
            xb[w][2][2*v+sub][j] = fmaxf(acc1[v], 0.f);
        }
    }

    // ---- phase 2: f=relu(W2@t)*BN; m = adj*f0+radj*f1 (self overwrite) ----
    {
        float a0[V], a1[V];
        float b0 = p.n0_b2[j], b1 = p.n1_b2[j];
        #pragma unroll
        for (int v = 0; v < V; v++) { a0[v] = b0; a1[v] = b1; }
        #pragma unroll
        for (int kc = 0; kc < 8; kc++) {
            float4 w0 = *(const float4*)&Wq[2048 + kc*128 + j*4];
            float4 w1 = *(const float4*)&Wq[3072 + kc*128 + j*4];
            #pragma unroll
            for (int v = 0; v < V; v++) {
                float4 va = *(const float4*)&xb[w][1][2*v+sub][kc*4];
                float4 vb = *(const float4*)&xb[w][2][2*v+sub][kc*4];
                a0[v] += dot4(w0, va);
                a1[v] += dot4(w1, vb);
            }
        }
        #pragma unroll
        for (int v = 0; v < V; v++) {
            float f0 = fmaxf(a0[v], 0.f) * BN_SCALEF;
            float f1 = fmaxf(a1[v], 0.f) * BN_SCALEF;
            float m = adjv[v]*f0 + radjv[v]*f1;
            if (cv[v] == qtv[v]) m = p.perb[pbase + bv[v]*96 + 64 + j];
            xb[w][1][2*v+sub][j] = m;
        }
    }

    // ---- phase 3: edge attention -> m' in xb[2] ----
    {
        float e[V], aa[V];
        float be = p.ea_eb[j], ba = p.ea_ab[j];
        #pragma unroll
        for (int v = 0; v < V; v++) { e[v] = be; aa[v] = ba; }
        #pragma unroll
        for (int kc = 0; kc < 8; kc++) {
            float4 we = *(const float4*)&Wq[4096 + kc*128 + j*4];
            float4 wa = *(const float4*)&Wq[5120 + kc*128 + j*4];
            #pragma unroll
            for (int v = 0; v < V; v++) {
                float4 vm = *(const float4*)&xb[w][1][2*v+sub][kc*4];
                e[v]  += dot4(we, vm);
                aa[v] += dot4(wa, vm);
            }
        }
        #pragma unroll
        for (int v = 0; v < V; v++) {
            float eg = sigm(e[v]);
            float af = tanhfast(aa[v]);
            float wc = p.ea_w[cv[v]];
            float m  = xb[w][1][2*v+sub][j];
            xb[w][2][2*v+sub][j] = m - wc*eg*m + wc*af;
        }
    }

    // ---- phase 4b: GRU ih gates from m'; combine with gh regs; write ht ----
    float hn[V];
    {
        float gi0[V], gi1[V], gi2[V];
        float bi0 = p.gru_b_ih[j], bi1 = p.gru_b_ih[32+j], bi2 = p.gru_b_ih[64+j];
        #pragma unroll
        for (int v = 0; v < V; v++) { gi0[v]=bi0; gi1[v]=bi1; gi2[v]=bi2; }
        #pragma unroll
        for (int kc = 0; kc < 8; kc++) {
            const float* wi = &Wq[6144 + kc*384];
            float4 wi0 = *(const float4*)&wi[j*4];
            float4 wi1 = *(const float4*)&wi[(32+j)*4];
            float4 wi2 = *(const float4*)&wi[(64+j)*4];
            #pragma unroll
            for (int v = 0; v < V; v++) {
                float4 vm = *(const float4*)&xb[w][2][2*v+sub][kc*4];
                gi0[v] += dot4(wi0, vm);
                gi1[v] += dot4(wi1, vm);
                gi2[v] += dot4(wi2, vm);
            }
        }
        #pragma unroll
        for (int v = 0; v < V; v++) {
            float r = sigm(gi0[v] + gh0[v]);
            float z = sigm(gi1[v] + gh1[v]);
            float n = tanhfast(gi2[v] + r*gh2[v]);
            hn[v] = (1.f - z)*n + z*hj[v];
            int node = nodebase + 2*v + sub;
            p.ht[node*32 + j] = hn[v];
        }
    }

    // ---- phase 5: prediction + per-b prep for step t+1 ----
    #pragma unroll
    for (int v = 0; v < V; v++) {
        int qn = p.questions[bv[v]*TT + t + 1];
        if (cv[v] == qn) {                  // uniform within 32-lane half
            float s = hn[v] * p.pred_w[j];
            #pragma unroll
            for (int off = 16; off; off >>= 1) s += __shfl_down(s, off, 32);
            if (j == 0) p.out[bv[v]*(TT-1) + t] = sigm(s + p.pred_b[0]);

            if (t < TT - 2) {
                int xt1 = p.features[bv[v]*TT + t + 1];
                float eq = p.emb_x[xt1*32 + j];
                float accA0 = p.n0_b1[j], accA1 = p.n1_b1[j], accS = p.self_b1[j];
                #pragma unroll
                for (int k = 0; k < 32; k++) {
                    float hk = __shfl(hn[v], k, 32);
                    float ek = __shfl(eq, k, 32);
                    accA0 += p.n0_w1[j*128 + k]*hk + p.n0_w1[j*128 + 32 + k]*ek;
                    accA1 += p.n1_w1[j*128 + k]*hk + p.n1_w1[j*128 + 32 + k]*ek;
                    accS  += p.self_w1[j*64 + k]*hk + p.self_w1[j*64 + 32 + k]*ek;
                }
                float l1 = fmaxf(accS, 0.f);
                float s2 = p.self_b2[j];
                #pragma unroll
                for (int k = 0; k < 32; k++) s2 += p.self_w2[j*32 + k] * __shfl(l1, k, 32);
                float* pn = p.perb + ((t+1) & 1)*PERB_BUF + bv[v]*96;
                pn[j]      = accA0;
                pn[32 + j] = accA1;
                pn[64 + j] = fmaxf(s2, 0.f) * BN_SCALEF;
            }
        }
    }
}

extern "C" void kernel_launch(void* const* d_in, const int* in_sizes, int n_in,
                              void* d_out, int out_size, void* d_ws, size_t ws_size,
                              hipStream_t stream) {
    Params prm;
    prm.features = (const int*)  d_in[0];
    prm.questions= (const int*)  d_in[1];
    prm.graph    = (const float*)d_in[2];
    prm.emb_x    = (const float*)d_in[3];
    const float* emb_c = (const float*)d_in[4];
    prm.self_w1  = (const float*)d_in[5];
    prm.self_b1  = (const float*)d_in[6];
    prm.self_w2  = (const float*)d_in[7];
    prm.self_b2  = (const float*)d_in[8];
    prm.n0_w1    = (const float*)d_in[9];
    prm.n0_b1    = (const float*)d_in[10];
    prm.n0_w2    = (const float*)d_in[11];
    prm.n0_b2    = (const float*)d_in[12];
    prm.n1_w1    = (const float*)d_in[13];
    prm.n1_b1    = (const float*)d_in[14];
    prm.n1_w2    = (const float*)d_in[15];
    prm.n1_b2    = (const float*)d_in[16];
    prm.ea_w     = (const float*)d_in[17];
    prm.ea_ew    = (const float*)d_in[18];
    prm.ea_eb    = (const float*)d_in[19];
    prm.ea_aw    = (const float*)d_in[20];
    prm.ea_ab    = (const float*)d_in[21];
    prm.gru_w_ih = (const float*)d_in[22];
    prm.gru_w_hh = (const float*)d_in[23];
    prm.gru_b_ih = (const float*)d_in[24];
    prm.gru_b_hh = (const float*)d_in[25];
    prm.pred_w   = (const float*)d_in[26];
    prm.pred_b   = (const float*)d_in[27];
    prm.out = (float*)d_out;

    float* ws   = (float*)d_ws;
    prm.ht      = ws;
    float* P0   = prm.ht + HT_SZ;
    float* P1   = P0 + P_SZ;
    float* gT   = P1 + P_SZ;
    float* perb = gT + GT_SZ;
    float* wpack= perb + 2*PERB_BUF;
    prm.P0 = P0; prm.P1 = P1; prm.graphT = gT; prm.perb = perb; prm.wpack = wpack;

    init0_kernel<<<(HT_SZ + 255)/256, 256, 0, stream>>>(prm.graph, gT, prm.ht);
    pk_kernel<<<CC, 64, 0, stream>>>(prm.n0_w1, prm.n1_w1, emb_c, P0, P1);
    pack_kernel<<<1, 256, 0, stream>>>(prm.n0_w1, prm.n1_w1, prm.n0_w2, prm.n1_w2,
                                       prm.ea_ew, prm.ea_aw, prm.gru_w_ih, prm.gru_w_hh,
                                       wpack);
    perb0_kernel<<<1, 1024, 0, stream>>>(prm.features, prm.emb_x,
        prm.n0_w1, prm.n0_b1, prm.n1_w1, prm.n1_b1,
        prm.self_w1, prm.self_b1, prm.self_w2, prm.self_b2, perb);

    for (int t = 0; t < NSTEP; t++) {
        step_kernel<<<NBLK, NTH, 0, stream>>>(t, prm);
    }
}